// Round 2
// 621.900 us; speedup vs baseline: 1.1271x; 1.1271x over previous
//
#include <hip/hip_runtime.h>
#include <hip/hip_bf16.h>
#include <math.h>
#include <stdint.h>

#define B_SZ 256
#define H_SZ 1024
#define L_SZ 10
#define V_SZ 50257

typedef __attribute__((ext_vector_type(8))) short short8;
typedef __attribute__((ext_vector_type(4))) float floatx4;

// fp32 -> bf16 bits, round-to-nearest-even (scalar path, used in gru_combine)
__device__ __forceinline__ unsigned f2bf_bits(float f) {
    unsigned u = __float_as_uint(f);
    return (u + 0x7FFFu + ((u >> 16) & 1u)) >> 16;
}

// 8x fp32 -> 8x bf16 via v_cvt_pk_bf16_f32 (4 instrs instead of ~40 VALU ops).
// gfx950 has the instruction but no builtin (learn_hip m240 / T12 recipe).
__device__ __forceinline__ short8 cvt8(float4 a, float4 b) {
    unsigned r0, r1, r2, r3;
    asm("v_cvt_pk_bf16_f32 %0, %1, %2" : "=v"(r0) : "v"(a.x), "v"(a.y));
    asm("v_cvt_pk_bf16_f32 %0, %1, %2" : "=v"(r1) : "v"(a.z), "v"(a.w));
    asm("v_cvt_pk_bf16_f32 %0, %1, %2" : "=v"(r2) : "v"(b.x), "v"(b.y));
    asm("v_cvt_pk_bf16_f32 %0, %1, %2" : "=v"(r3) : "v"(b.z), "v"(b.w));
    union { unsigned u[4]; short8 s; } u;
    u.u[0] = r0; u.u[1] = r1; u.u[2] = r2; u.u[3] = r3;
    return u.s;
}

// ---------------------------------------------------------------------------
// MFMA GEMM: C[M,N] = A[M,K] @ W[N,K]^T + bias (optional relu).
// 256 threads = 4 waves. Block tile: (MSUB*64) x 64, k-chunk 32.
//
// Software pipeline:
//   - PF register buffers of W fp32 (PF chunks in flight to HBM),
//   - double-buffered bf16 LDS (WSTRIDE=40 -> 2-way bank aliasing, free),
//   - ONE raw s_barrier per chunk with manual lgkmcnt(0); NO __syncthreads,
//     so the compiler's vmcnt waits stay COUNTED and prefetched chunks stay
//     in flight across barriers (avoids the vmcnt(0)-drain-at-barrier stall).
// Stage p invariant (chunk c = c0+p):
//   LDS[c&1] holds chunk c (barrier'd); wreg[(p+1)%PF..] hold chunks
//   c+1..c+PF-1 in flight; wreg[p] free.
// Stage body: issue chunk c+PF -> wreg[p]; compute chunk c from LDS[c&1];
//   cvt+ds_write chunk c+1 -> LDS[(c+1)&1]; lgkmcnt(0); s_barrier.
// RAW: chunk c written stage c-1 step 3, lgkmcnt(0)+barrier before stage c
//   reads it. WAR: stage c's ds_reads drained by the same lgkmcnt(0) before
//   the barrier that precedes stage c+1's overwrite.
// Requires: nc % PF == 0, nc >= PF (K=1024/2048 -> nc=32/64, PF in {2,4}).
//
// ABF=1: A is pre-converted bf16 [M,K] -> direct short8 loads, no cvt.
// Fragment layouts (verified, learn_hip m89/m91):
//   A/B operand: elem [row = lane&15][k = (lane>>4)*8 + j]
//   C/D:         row = (lane>>4)*4 + reg, col = lane&15
// ---------------------------------------------------------------------------
#define WSTRIDE 40

template<int MSUB, int RELU, int PF, int ABF>
__device__ __forceinline__ void gemm_body(
    short (*lwb)[64 * WSTRIDE],
    const void* __restrict__ A, const float* __restrict__ W,
    const float* __restrict__ bias, float* __restrict__ C,
    int N, int K)
{
    const int tid  = threadIdx.x;
    const int wave = tid >> 6;
    const int lane = tid & 63;
    const int quad = lane >> 4;
    const int l16  = lane & 15;

    const int n0 = blockIdx.x * 64;
    const int m_base = blockIdx.y * (MSUB * 64) + wave * (MSUB * 16);

    // W staging: thread t loads row (t>>2), 8 floats at col (t&3)*8.
    // OOB rows clamp to N-1 (harmless garbage; epilogue masks on n<N).
    const int wr = tid >> 2;
    const int wc = (tid & 3) * 8;
    int wrow = n0 + wr;
    if (wrow >= N) wrow = N - 1;
    const float* wp = W + (size_t)wrow * K + wc;

    const int nc = K >> 5;

    const float* af[MSUB];
    const short* ab[MSUB];
#pragma unroll
    for (int ms = 0; ms < MSUB; ++ms) {
        int m = m_base + ms * 16 + l16;
        if (ABF) ab[ms] = (const short*)A + (size_t)m * K + quad * 8;
        else     af[ms] = (const float*)A + (size_t)m * K + quad * 8;
    }

    floatx4 zero = {0.f, 0.f, 0.f, 0.f};
    floatx4 acc[MSUB][4];
#pragma unroll
    for (int ms = 0; ms < MSUB; ++ms)
#pragma unroll
        for (int ns = 0; ns < 4; ++ns) acc[ms][ns] = zero;

    // ---- prologue: issue chunks 0..PF-1, stage chunk 0 into LDS[0] ----
    float4 wreg[PF][2];
#pragma unroll
    for (int p = 0; p < PF; ++p) {
        wreg[p][0] = *(const float4*)(wp + p * 32);
        wreg[p][1] = *(const float4*)(wp + p * 32 + 4);
    }
    *(short8*)&lwb[0][wr * WSTRIDE + wc] = cvt8(wreg[0][0], wreg[0][1]);
    asm volatile("s_waitcnt lgkmcnt(0)" ::: "memory");
    __builtin_amdgcn_s_barrier();

    // ---- main pipeline ----
    for (int c0 = 0; c0 < nc; c0 += PF) {
#pragma unroll
        for (int p = 0; p < PF; ++p) {
            const int c   = c0 + p;
            const int buf = p & 1;          // == c & 1 (PF even)

            // 1. prefetch chunk c+PF into wreg[p] (just freed)
            if (c + PF < nc) {
                wreg[p][0] = *(const float4*)(wp + (c + PF) * 32);
                wreg[p][1] = *(const float4*)(wp + (c + PF) * 32 + 4);
            }

            // 2. compute chunk c from LDS[buf]
            short8 bfrag[4];
#pragma unroll
            for (int ns = 0; ns < 4; ++ns)
                bfrag[ns] = *(const short8*)&lwb[buf][(ns * 16 + l16) * WSTRIDE + quad * 8];
#pragma unroll
            for (int ms = 0; ms < MSUB; ++ms) {
                short8 afrag;
                if (ABF) {
                    afrag = *(const short8*)(ab[ms] + c * 32);
                } else {
                    float4 a0 = *(const float4*)(af[ms] + c * 32);
                    float4 a1 = *(const float4*)(af[ms] + c * 32 + 4);
                    afrag = cvt8(a0, a1);
                }
#pragma unroll
                for (int ns = 0; ns < 4; ++ns)
                    acc[ms][ns] = __builtin_amdgcn_mfma_f32_16x16x32_bf16(
                        afrag, bfrag[ns], acc[ms][ns], 0, 0, 0);
            }

            // 3. stage chunk c+1 into LDS[buf^1] (compiler emits a COUNTED
            //    vmcnt here for wreg[q]'s loads — newer prefetches stay live)
            if (c + 1 < nc) {
                const int q = (p + 1 == PF) ? 0 : p + 1;
                *(short8*)&lwb[buf ^ 1][wr * WSTRIDE + wc] =
                    cvt8(wreg[q][0], wreg[q][1]);
            }

            // 4. make ds ops visible/drained, then raw barrier (no vmcnt drain)
            asm volatile("s_waitcnt lgkmcnt(0)" ::: "memory");
            __builtin_amdgcn_s_barrier();
        }
    }

    // ---- epilogue ----
    float bia[4];
#pragma unroll
    for (int ns = 0; ns < 4; ++ns) {
        int n = n0 + ns * 16 + l16;
        bia[ns] = (n < N) ? bias[n] : 0.f;
    }
#pragma unroll
    for (int ms = 0; ms < MSUB; ++ms) {
        int mb = m_base + ms * 16 + quad * 4;
#pragma unroll
        for (int ns = 0; ns < 4; ++ns) {
            int n = n0 + ns * 16 + l16;
            if (n < N) {
#pragma unroll
                for (int i = 0; i < 4; ++i) {
                    float v = acc[ms][ns][i] + bia[ns];
                    if (RELU) v = fmaxf(v, 0.f);
                    C[(size_t)(mb + i) * N + n] = v;
                }
            }
        }
    }
}

template<int MSUB, int RELU, int PF, int ABF>
__global__ __launch_bounds__(256) void gemm_mfma(
    const void* __restrict__ A, const float* __restrict__ W,
    const float* __restrict__ bias, float* __restrict__ C,
    int N, int K)
{
    __shared__ __align__(16) short lwb[2][64 * WSTRIDE];
    gemm_body<MSUB, RELU, PF, ABF>(lwb, A, W, bias, C, N, K);
}

// Two independent GEMMs (gi and gh) in ONE dispatch: blockIdx.z selects.
template<int MSUB, int RELU, int PF>
__global__ __launch_bounds__(256) void gemm_dual(
    const void* __restrict__ A0, const float* __restrict__ W0,
    const float* __restrict__ b0, float* __restrict__ C0,
    const void* __restrict__ A1, const float* __restrict__ W1,
    const float* __restrict__ b1, float* __restrict__ C1,
    int N, int K)
{
    __shared__ __align__(16) short lwb[2][64 * WSTRIDE];
    const void*  A = blockIdx.z ? A1 : A0;
    const float* W = blockIdx.z ? W1 : W0;
    const float* b = blockIdx.z ? b1 : b0;
    float*       C = blockIdx.z ? C1 : C0;
    gemm_body<MSUB, RELU, PF, 0>(lwb, A, W, b, C, N, K);
}

// ---------------------------------------------------------------------------
// Kernel 1: embedding gather + attention logits + softmax + context vector.
// ---------------------------------------------------------------------------
__global__ __launch_bounds__(256) void attn_kernel(
    const int* __restrict__ tokens, const float* __restrict__ hidden,
    const float* __restrict__ enc, const float* __restrict__ emb,
    const float* __restrict__ attn_W, const float* __restrict__ attn_b,
    float* __restrict__ cat_out, float* __restrict__ attn_w_out)
{
    const int b = blockIdx.x;
    const int tid = threadIdx.x;
    const int tok = tokens[b];
    const float* erow = emb + (size_t)tok * H_SZ;
    const float* hrow = hidden + (size_t)b * H_SZ;

    __shared__ float red[L_SZ][256];
    __shared__ float wts[L_SZ];

    float acc[L_SZ];
#pragma unroll
    for (int l = 0; l < L_SZ; ++l) acc[l] = 0.f;

    for (int i = tid; i < H_SZ; i += 256) {
        float e = erow[i];
        float hv = hrow[i];
        cat_out[(size_t)b * 2 * H_SZ + i] = e;
#pragma unroll
        for (int l = 0; l < L_SZ; ++l) {
            acc[l] += e * attn_W[l * 2 * H_SZ + i] + hv * attn_W[l * 2 * H_SZ + H_SZ + i];
        }
    }
#pragma unroll
    for (int l = 0; l < L_SZ; ++l) red[l][tid] = acc[l];
    __syncthreads();
    for (int s = 128; s > 0; s >>= 1) {
        if (tid < s) {
#pragma unroll
            for (int l = 0; l < L_SZ; ++l) red[l][tid] += red[l][tid + s];
        }
        __syncthreads();
    }
    if (tid == 0) {
        float m = -INFINITY;
        float lg[L_SZ];
#pragma unroll
        for (int l = 0; l < L_SZ; ++l) {
            lg[l] = red[l][0] + attn_b[l];
            m = fmaxf(m, lg[l]);
        }
        float s = 0.f;
#pragma unroll
        for (int l = 0; l < L_SZ; ++l) {
            float e = expf(lg[l] - m);
            wts[l] = e;
            s += e;
        }
        float inv = 1.f / s;
#pragma unroll
        for (int l = 0; l < L_SZ; ++l) {
            wts[l] *= inv;
            attn_w_out[(size_t)b * L_SZ + l] = wts[l];
        }
    }
    __syncthreads();

    for (int i = tid; i < H_SZ; i += 256) {
        float s = 0.f;
#pragma unroll
        for (int l = 0; l < L_SZ; ++l) s += wts[l] * enc[l * H_SZ + i];
        cat_out[(size_t)b * 2 * H_SZ + H_SZ + i] = s;
    }
}

// ---------------------------------------------------------------------------
// GRU pointwise combine (+ optional bf16 copy of h_new for the big GEMM's A)
// ---------------------------------------------------------------------------
__global__ __launch_bounds__(256) void gru_combine(
    const float* __restrict__ gi, const float* __restrict__ gh,
    const float* __restrict__ hidden, float* __restrict__ h_new,
    short* __restrict__ hb16)
{
    int idx = blockIdx.x * blockDim.x + threadIdx.x;
    if (idx >= B_SZ * H_SZ) return;
    int b = idx >> 10;
    int j = idx & (H_SZ - 1);
    const float* gib = gi + (size_t)b * 3 * H_SZ;
    const float* ghb = gh + (size_t)b * 3 * H_SZ;
    float i_r = gib[j], i_z = gib[H_SZ + j], i_n = gib[2 * H_SZ + j];
    float h_r = ghb[j], h_z = ghb[H_SZ + j], h_n = ghb[2 * H_SZ + j];
    float r = 1.f / (1.f + expf(-(i_r + h_r)));
    float z = 1.f / (1.f + expf(-(i_z + h_z)));
    float n = tanhf(i_n + r * h_n);
    float h = hidden[idx];
    float hn = (1.f - z) * n + z * h;
    h_new[idx] = hn;
    if (hb16) hb16[idx] = (short)f2bf_bits(hn);
}

// ---------------------------------------------------------------------------
// log-softmax, 2 passes, float4, online max+sum. One block (1024 thr) per row.
// ---------------------------------------------------------------------------
__global__ __launch_bounds__(1024) void logsoftmax_v2(float* __restrict__ out)
{
    const int b = blockIdx.x;
    float* row = out + (size_t)b * V_SZ;
    const int tid = threadIdx.x;
    const int wave = tid >> 6;
    const int lane = tid & 63;

    const int head = (int)(((16u - ((uintptr_t)row & 15u)) & 15u) >> 2);  // 0..3
    const int nv = (V_SZ - head) >> 2;
    const float4* r4 = (const float4*)(row + head);
    const int tail_start = head + (nv << 2);

    float m = -INFINITY, s = 0.f;
    if (tid < head) {
        float v = row[tid];
        m = v; s = 1.f;
    }
    for (int i = tid; i < nv; i += 1024) {
        float4 v = r4[i];
        float mv = fmaxf(fmaxf(v.x, v.y), fmaxf(v.z, v.w));
        if (mv > m) { s *= expf(m - mv); m = mv; }
        s += expf(v.x - m) + expf(v.y - m) + expf(v.z - m) + expf(v.w - m);
    }
    for (int i = tail_start + tid; i < V_SZ; i += 1024) {
        float v = row[i];
        if (v > m) { s *= expf(m - v); m = v; }
        s += expf(v - m);
    }

    for (int off = 32; off > 0; off >>= 1) {
        float m2 = __shfl_down(m, off);
        float s2 = __shfl_down(s, off);
        float mn = fmaxf(m, m2);
        s = s * expf(m - mn) + s2 * expf(m2 - mn);
        m = mn;
    }
    __shared__ float smax[16], ssum[16], slse;
    if (lane == 0) { smax[wave] = m; ssum[wave] = s; }
    __syncthreads();
    if (tid == 0) {
        float M = smax[0], S = ssum[0];
        for (int w = 1; w < 16; ++w) {
            float mn = fmaxf(M, smax[w]);
            S = S * expf(M - mn) + ssum[w] * expf(smax[w] - mn);
            M = mn;
        }
        slse = M + logf(S);
    }
    __syncthreads();
    const float lse = slse;

    if (tid < head) row[tid] -= lse;
    float4* w4 = (float4*)(row + head);
    for (int i = tid; i < nv; i += 1024) {
        float4 v = r4[i];
        v.x -= lse; v.y -= lse; v.z -= lse; v.w -= lse;
        w4[i] = v;
    }
    for (int i = tail_start + tid; i < V_SZ; i += 1024) row[i] -= lse;
}

// ---------------------------------------------------------------------------
extern "C" void kernel_launch(void* const* d_in, const int* in_sizes, int n_in,
                              void* d_out, int out_size, void* d_ws, size_t ws_size,
                              hipStream_t stream)
{
    const int*   tokens = (const int*)d_in[0];
    const float* hidden = (const float*)d_in[1];
    const float* enc    = (const float*)d_in[2];
    const float* emb    = (const float*)d_in[3];
    const float* attn_W = (const float*)d_in[4];
    const float* attn_b = (const float*)d_in[5];
    const float* comb_W = (const float*)d_in[6];
    const float* comb_b = (const float*)d_in[7];
    const float* W_ih   = (const float*)d_in[8];
    const float* W_hh   = (const float*)d_in[9];
    const float* b_ih   = (const float*)d_in[10];
    const float* b_hh   = (const float*)d_in[11];
    const float* out_W  = (const float*)d_in[12];
    const float* out_b  = (const float*)d_in[13];

    float* out = (float*)d_out;
    float* logits     = out;                                   // [B,V]
    float* h_new      = out + (size_t)B_SZ * V_SZ;             // [B,H]
    float* attn_w_out = h_new + (size_t)B_SZ * H_SZ;           // [B,L]

    // Scratch: prefer workspace (lets the big GEMM read bf16 A while it
    // overwrites the logits region). Fallback: carve from logits region
    // (dead before the big GEMM), fp32 A path.
    const size_t need = (size_t)B_SZ * H_SZ * 9 * sizeof(float)   // cat+x+gi+gh
                      + (size_t)B_SZ * H_SZ * sizeof(short);      // h_bf16
    const bool use_ws = (d_ws != nullptr) && (ws_size >= need);

    float* scratch = use_ws ? (float*)d_ws : logits;
    float* cat = scratch;                          // [B, 2H]
    float* x   = cat + (size_t)B_SZ * 2 * H_SZ;    // [B, H]
    float* gi  = x   + (size_t)B_SZ * H_SZ;        // [B, 3H]
    float* gh  = gi  + (size_t)B_SZ * 3 * H_SZ;    // [B, 3H]
    short* hb16 = use_ws ? (short*)(gh + (size_t)B_SZ * 3 * H_SZ) : nullptr;

    attn_kernel<<<B_SZ, 256, 0, stream>>>(tokens, hidden, enc, emb, attn_W, attn_b,
                                          cat, attn_w_out);
    // x = relu(cat @ comb_W^T + comb_b)          [256 x 1024, K=2048]
    gemm_mfma<1, 1, 4, 0><<<dim3(H_SZ / 64, 4), 256, 0, stream>>>(
        cat, comb_W, comb_b, x, H_SZ, 2 * H_SZ);
    // gi = x @ W_ih^T + b_ih ; gh = h @ W_hh^T + b_hh   (one dispatch, z=2)
    gemm_dual<1, 0, 4><<<dim3(3 * H_SZ / 64, 4, 2), 256, 0, stream>>>(
        x, W_ih, b_ih, gi,
        hidden, W_hh, b_hh, gh, 3 * H_SZ, H_SZ);
    gru_combine<<<(B_SZ * H_SZ + 255) / 256, 256, 0, stream>>>(gi, gh, hidden,
                                                               h_new, hb16);
    // logits = h_new @ out_W^T + out_b           [256 x 50257, K=1024]
    if (use_ws)
        gemm_mfma<4, 0, 2, 1><<<dim3((V_SZ + 63) / 64, 1), 256, 0, stream>>>(
            (const void*)hb16, out_W, out_b, logits, V_SZ, H_SZ);
    else
        gemm_mfma<4, 0, 2, 0><<<dim3((V_SZ + 63) / 64, 1), 256, 0, stream>>>(
            (const void*)h_new, out_W, out_b, logits, V_SZ, H_SZ);
    logsoftmax_v2<<<B_SZ, 1024, 0, stream>>>(logits);
}

// Round 3
// 584.013 us; speedup vs baseline: 1.2002x; 1.0649x over previous
//
#include <hip/hip_runtime.h>
#include <math.h>
#include <stdint.h>

#define B_SZ 256
#define H_SZ 1024
#define L_SZ 10
#define V_SZ 50257

typedef __attribute__((ext_vector_type(8))) short short8;
typedef __attribute__((ext_vector_type(4))) float floatx4;

// fp32 -> bf16 bits, round-to-nearest-even (scalar)
__device__ __forceinline__ unsigned f2bf_bits(float f) {
    unsigned u = __float_as_uint(f);
    return (u + 0x7FFFu + ((u >> 16) & 1u)) >> 16;
}

// 8x fp32 -> 8x bf16 via v_cvt_pk_bf16_f32 (T12 primitive; RNE, matches f2bf_bits)
__device__ __forceinline__ short8 cvt8(float4 a, float4 b) {
    unsigned r0, r1, r2, r3;
    asm("v_cvt_pk_bf16_f32 %0, %1, %2" : "=v"(r0) : "v"(a.x), "v"(a.y));
    asm("v_cvt_pk_bf16_f32 %0, %1, %2" : "=v"(r1) : "v"(a.z), "v"(a.w));
    asm("v_cvt_pk_bf16_f32 %0, %1, %2" : "=v"(r2) : "v"(b.x), "v"(b.y));
    asm("v_cvt_pk_bf16_f32 %0, %1, %2" : "=v"(r3) : "v"(b.z), "v"(b.w));
    union { unsigned u[4]; short8 s; } u;
    u.u[0] = r0; u.u[1] = r1; u.u[2] = r2; u.u[3] = r3;
    return u.s;
}

// async global->LDS DMA, 16B per lane, dest = wave-uniform base + lane*16
__device__ __forceinline__ void glds16(const void* g, void* l) {
    __builtin_amdgcn_global_load_lds(
        (const __attribute__((address_space(1))) void*)g,
        (__attribute__((address_space(3))) void*)l, 16, 0, 0);
}

template<int N> __device__ __forceinline__ void waitvm() {
    if constexpr (N == 0)       asm volatile("s_waitcnt vmcnt(0)" ::: "memory");
    else if constexpr (N == 3)  asm volatile("s_waitcnt vmcnt(3)" ::: "memory");
    else if constexpr (N == 4)  asm volatile("s_waitcnt vmcnt(4)" ::: "memory");
    else if constexpr (N == 6)  asm volatile("s_waitcnt vmcnt(6)" ::: "memory");
    else if constexpr (N == 8)  asm volatile("s_waitcnt vmcnt(8)" ::: "memory");
    else if constexpr (N == 9)  asm volatile("s_waitcnt vmcnt(9)" ::: "memory");
    else if constexpr (N == 10) asm volatile("s_waitcnt vmcnt(10)" ::: "memory");
    else if constexpr (N == 12) asm volatile("s_waitcnt vmcnt(12)" ::: "memory");
    else if constexpr (N == 20) asm volatile("s_waitcnt vmcnt(20)" ::: "memory");
    else static_assert(N == 0, "unsupported vmcnt literal");
}

// ---------------------------------------------------------------------------
// MFMA GEMM: C[M,N] = A[M,K] @ W[N,K]^T + bias (optional relu).
// 256 threads = 4 waves. Block tile (MSUB*64) x 64, k-chunk 32.
//
// m97 structure: BOTH operands staged via global_load_lds (fire-and-forget),
// DEPTH ring buffers, ONE counted vmcnt per chunk (never 0 mid-loop),
// raw s_barrier (asm, "memory") — no register-load waits in the loop, so the
// DMA queue stays DEPTH-1 chunks deep (fixes round-2's in-order-vmcnt drain).
//
// Per-chunk, per-wave DMA ops (vmcnt units): W=2, A = ABF ? MSUB : 2*MSUB.
// Chunk c is complete when <= OPS*(DEPTH-1) ops remain outstanding (tail
// iterations use the shrunken count). Barrier1 after the wait makes all
// waves' staging visible; barrier2 (after lgkmcnt(0)) closes the WAR before
// reusing the slot.
//
// LDS swizzle (rule #21, both-sides): global_load_lds writes linearly
// (base + lane*16), so the XOR swizzle is applied to the per-lane GLOBAL
// source granule and the same XOR on the ds_read side:
//   fp32 [rows][32] tile (128B row, 8 granules): slot g holds src granule
//     g ^ (row&7); staging lane L: row&7 == L>>3, src granule (L&7)^(L>>3).
//   bf16 [rows][32] tile (64B row, 4 granules): slot g holds src granule
//     g ^ ((row>>1)&3); staging lane L: src granule (L&3)^((L>>3)&3).
// Fragment layouts (verified, learn_hip m89/m91):
//   A/B operand: elem [row = lane&15][k = (lane>>4)*8 + j]
//   C/D:         row = (lane>>4)*4 + reg, col = lane&15
// ---------------------------------------------------------------------------
template<int MSUB, int RELU, int DEPTH, int ABF>
__device__ __forceinline__ void gemm_body(
    float* wbuf, short* abufS, float* abufF,
    const void* __restrict__ A, const float* __restrict__ W,
    const float* __restrict__ bias, float* __restrict__ Cf,
    short* __restrict__ C16, int N, int K)
{
    constexpr int AOPS = ABF ? MSUB : 2 * MSUB;
    constexpr int OPS  = 2 + AOPS;

    const int tid  = threadIdx.x;
    const int wave = tid >> 6;
    const int lane = tid & 63;
    const int quad = lane >> 4;
    const int l16  = lane & 15;

    const int n0 = blockIdx.x * 64;
    const int m_base = blockIdx.y * (MSUB * 64) + wave * (MSUB * 16);
    const int nc = K >> 5;

    // ---- staging source pointers (pre-swizzled granules) ----
    const float* wsrc[2];
#pragma unroll
    for (int i = 0; i < 2; ++i) {
        int row = n0 + 8 * (2 * wave + i) + (lane >> 3);
        if (row >= N) row = N - 1;                      // clamp; epilogue masks
        wsrc[i] = W + (size_t)row * K + (((lane & 7) ^ (lane >> 3)) << 2);
    }
    const short* asrcS[ABF ? MSUB : 1];
    const float* asrcF[ABF ? 1 : 2 * MSUB];
    if constexpr (ABF) {
#pragma unroll
        for (int j = 0; j < MSUB; ++j) {
            int row = m_base + 16 * j + (lane >> 2);
            asrcS[j] = (const short*)A + (size_t)row * K
                     + (((lane & 3) ^ ((lane >> 3) & 3)) << 3);
        }
    } else {
#pragma unroll
        for (int j = 0; j < 2 * MSUB; ++j) {
            int row = m_base + 8 * j + (lane >> 3);
            asrcF[j] = (const float*)A + (size_t)row * K
                     + (((lane & 7) ^ (lane >> 3)) << 2);
        }
    }

    // ---- read byte-offsets (swizzled) ----
    int boff[4][2];
#pragma unroll
    for (int ns = 0; ns < 4; ++ns) {
        int R = ns * 16 + l16;
#pragma unroll
        for (int h = 0; h < 2; ++h)
            boff[ns][h] = R * 128 + (((2 * quad + h) ^ (l16 & 7)) << 4);
    }
    int aoff[MSUB][2];
#pragma unroll
    for (int ms = 0; ms < MSUB; ++ms) {
        int Rl = wave * MSUB * 16 + ms * 16 + l16;      // tile-local row
        if constexpr (ABF) {
            aoff[ms][0] = Rl * 64 + ((quad ^ ((l16 >> 1) & 3)) << 4);
            aoff[ms][1] = 0;
        } else {
#pragma unroll
            for (int h = 0; h < 2; ++h)
                aoff[ms][h] = Rl * 128 + (((2 * quad + h) ^ (l16 & 7)) << 4);
        }
    }

    floatx4 zero = {0.f, 0.f, 0.f, 0.f};
    floatx4 acc[MSUB][4];
#pragma unroll
    for (int ms = 0; ms < MSUB; ++ms)
#pragma unroll
        for (int ns = 0; ns < 4; ++ns) acc[ms][ns] = zero;

    auto issue = [&](int slot) {
#pragma unroll
        for (int i = 0; i < 2; ++i) {
            glds16(wsrc[i], (char*)wbuf + slot * 8192 + (2 * wave + i) * 1024);
            wsrc[i] += 32;
        }
        if constexpr (ABF) {
#pragma unroll
            for (int j = 0; j < MSUB; ++j) {
                glds16(asrcS[j], (char*)abufS + slot * (MSUB * 4096)
                                 + (wave * MSUB + j) * 1024);
                asrcS[j] += 32;
            }
        } else {
#pragma unroll
            for (int j = 0; j < 2 * MSUB; ++j) {
                glds16(asrcF[j], (char*)abufF + slot * (MSUB * 8192)
                                 + (wave * 2 * MSUB + j) * 1024);
                asrcF[j] += 32;
            }
        }
    };

    // ---- prologue: fill all DEPTH slots (nc >= DEPTH for all our shapes) ----
#pragma unroll
    for (int d = 0; d < DEPTH; ++d) issue(d);

    // ---- main loop: one counted vmcnt + 2 cheap barriers per chunk ----
    int slot = 0;
    for (int c = 0; c < nc; ++c) {
        const int rem = nc - 1 - c;                     // chunks issued after c
        if (rem >= DEPTH - 1)  waitvm<OPS * (DEPTH - 1)>();
        else if (rem == 2)     waitvm<((DEPTH >= 4) ? 2 * OPS : 0)>();
        else if (rem == 1)     waitvm<((DEPTH >= 3) ? OPS : 0)>();
        else                   waitvm<0>();
        asm volatile("s_barrier" ::: "memory");          // chunk c visible to all

        const char* wb = (const char*)wbuf + slot * 8192;
        short8 bfr[4];
#pragma unroll
        for (int ns = 0; ns < 4; ++ns) {
            float4 x0 = *(const float4*)(wb + boff[ns][0]);
            float4 x1 = *(const float4*)(wb + boff[ns][1]);
            bfr[ns] = cvt8(x0, x1);
        }
        short8 afr[MSUB];
        if constexpr (ABF) {
            const char* ab = (const char*)abufS + slot * (MSUB * 4096);
#pragma unroll
            for (int ms = 0; ms < MSUB; ++ms)
                afr[ms] = *(const short8*)(ab + aoff[ms][0]);
        } else {
            const char* ab = (const char*)abufF + slot * (MSUB * 8192);
#pragma unroll
            for (int ms = 0; ms < MSUB; ++ms) {
                float4 a0 = *(const float4*)(ab + aoff[ms][0]);
                float4 a1 = *(const float4*)(ab + aoff[ms][1]);
                afr[ms] = cvt8(a0, a1);
            }
        }
#pragma unroll
        for (int ms = 0; ms < MSUB; ++ms)
#pragma unroll
            for (int ns = 0; ns < 4; ++ns)
                acc[ms][ns] = __builtin_amdgcn_mfma_f32_16x16x32_bf16(
                    afr[ms], bfr[ns], acc[ms][ns], 0, 0, 0);

        asm volatile("s_waitcnt lgkmcnt(0)" ::: "memory"); // my ds_reads done
        asm volatile("s_barrier" ::: "memory");            // everyone's done
        if (c + DEPTH < nc) issue(slot);                   // reuse slot (WAR closed)
        if (++slot == DEPTH) slot = 0;
    }

    // ---- epilogue ----
    float bia[4];
#pragma unroll
    for (int ns = 0; ns < 4; ++ns) {
        int n = n0 + ns * 16 + l16;
        bia[ns] = (n < N) ? bias[n] : 0.f;
    }
#pragma unroll
    for (int ms = 0; ms < MSUB; ++ms) {
        int mb = m_base + ms * 16 + quad * 4;
#pragma unroll
        for (int ns = 0; ns < 4; ++ns) {
            int n = n0 + ns * 16 + l16;
            if (n < N) {
#pragma unroll
                for (int i = 0; i < 4; ++i) {
                    float v = acc[ms][ns][i] + bia[ns];
                    if (RELU) v = fmaxf(v, 0.f);
                    if (Cf)  Cf[(size_t)(mb + i) * N + n] = v;
                    if (C16) C16[(size_t)(mb + i) * N + n] = (short)f2bf_bits(v);
                }
            }
        }
    }
}

template<int MSUB, int RELU, int DEPTH, int ABF>
__global__ __launch_bounds__(256) void gemm_k(
    const void* __restrict__ A, const float* __restrict__ W,
    const float* __restrict__ bias, float* __restrict__ Cf,
    short* __restrict__ C16, int N, int K)
{
    __shared__ __align__(16) float wbuf[DEPTH * 64 * 32];
    __shared__ __align__(16) short abufS[ABF ? DEPTH * MSUB * 2048 : 8];
    __shared__ __align__(16) float abufF[ABF ? 8 : DEPTH * MSUB * 2048];
    gemm_body<MSUB, RELU, DEPTH, ABF>(wbuf, abufS, abufF, A, W, bias, Cf, C16, N, K);
}

// Two independent GEMMs (gi and gh) in ONE dispatch: blockIdx.z selects.
template<int MSUB, int RELU, int DEPTH, int ABF>
__global__ __launch_bounds__(256) void gemm_dual(
    const void* __restrict__ A0, const float* __restrict__ W0,
    const float* __restrict__ b0, float* __restrict__ C0,
    const void* __restrict__ A1, const float* __restrict__ W1,
    const float* __restrict__ b1, float* __restrict__ C1,
    int N, int K)
{
    __shared__ __align__(16) float wbuf[DEPTH * 64 * 32];
    __shared__ __align__(16) short abufS[ABF ? DEPTH * MSUB * 2048 : 8];
    __shared__ __align__(16) float abufF[ABF ? 8 : DEPTH * MSUB * 2048];
    const void*  A = blockIdx.z ? A1 : A0;
    const float* W = blockIdx.z ? W1 : W0;
    const float* b = blockIdx.z ? b1 : b0;
    float*       C = blockIdx.z ? C1 : C0;
    gemm_body<MSUB, RELU, DEPTH, ABF>(wbuf, abufS, abufF, A, W, b, C, nullptr, N, K);
}

// ---------------------------------------------------------------------------
// Kernel 1: embedding gather + attention logits + softmax + context vector.
// Also emits bf16 copies of cat (for comb GEMM A) and hidden (for gh GEMM A).
// ---------------------------------------------------------------------------
__global__ __launch_bounds__(256) void attn_kernel(
    const int* __restrict__ tokens, const float* __restrict__ hidden,
    const float* __restrict__ enc, const float* __restrict__ emb,
    const float* __restrict__ attn_W, const float* __restrict__ attn_b,
    float* __restrict__ catf, short* __restrict__ cat16,
    short* __restrict__ h16, float* __restrict__ attn_w_out)
{
    const int b = blockIdx.x;
    const int tid = threadIdx.x;
    const int tok = tokens[b];
    const float* erow = emb + (size_t)tok * H_SZ;
    const float* hrow = hidden + (size_t)b * H_SZ;

    __shared__ float red[L_SZ][256];
    __shared__ float wts[L_SZ];

    float acc[L_SZ];
#pragma unroll
    for (int l = 0; l < L_SZ; ++l) acc[l] = 0.f;

    for (int i = tid; i < H_SZ; i += 256) {
        float e = erow[i];
        float hv = hrow[i];
        if (catf)  catf[(size_t)b * 2 * H_SZ + i] = e;
        if (cat16) cat16[(size_t)b * 2 * H_SZ + i] = (short)f2bf_bits(e);
        if (h16)   h16[(size_t)b * H_SZ + i] = (short)f2bf_bits(hv);
#pragma unroll
        for (int l = 0; l < L_SZ; ++l) {
            acc[l] += e * attn_W[l * 2 * H_SZ + i] + hv * attn_W[l * 2 * H_SZ + H_SZ + i];
        }
    }
#pragma unroll
    for (int l = 0; l < L_SZ; ++l) red[l][tid] = acc[l];
    __syncthreads();
    for (int s = 128; s > 0; s >>= 1) {
        if (tid < s) {
#pragma unroll
            for (int l = 0; l < L_SZ; ++l) red[l][tid] += red[l][tid + s];
        }
        __syncthreads();
    }
    if (tid == 0) {
        float m = -INFINITY;
        float lg[L_SZ];
#pragma unroll
        for (int l = 0; l < L_SZ; ++l) {
            lg[l] = red[l][0] + attn_b[l];
            m = fmaxf(m, lg[l]);
        }
        float s = 0.f;
#pragma unroll
        for (int l = 0; l < L_SZ; ++l) {
            float e = expf(lg[l] - m);
            wts[l] = e;
            s += e;
        }
        float inv = 1.f / s;
#pragma unroll
        for (int l = 0; l < L_SZ; ++l) {
            wts[l] *= inv;
            attn_w_out[(size_t)b * L_SZ + l] = wts[l];
        }
    }
    __syncthreads();

    for (int i = tid; i < H_SZ; i += 256) {
        float s = 0.f;
#pragma unroll
        for (int l = 0; l < L_SZ; ++l) s += wts[l] * enc[l * H_SZ + i];
        if (catf)  catf[(size_t)b * 2 * H_SZ + H_SZ + i] = s;
        if (cat16) cat16[(size_t)b * 2 * H_SZ + H_SZ + i] = (short)f2bf_bits(s);
    }
}

// ---------------------------------------------------------------------------
// GRU pointwise combine (+ optional bf16 copy of h_new for the big GEMM's A)
// ---------------------------------------------------------------------------
__global__ __launch_bounds__(256) void gru_combine(
    const float* __restrict__ gi, const float* __restrict__ gh,
    const float* __restrict__ hidden, float* __restrict__ h_new,
    short* __restrict__ hb16)
{
    int idx = blockIdx.x * blockDim.x + threadIdx.x;
    if (idx >= B_SZ * H_SZ) return;
    int b = idx >> 10;
    int j = idx & (H_SZ - 1);
    const float* gib = gi + (size_t)b * 3 * H_SZ;
    const float* ghb = gh + (size_t)b * 3 * H_SZ;
    float i_r = gib[j], i_z = gib[H_SZ + j], i_n = gib[2 * H_SZ + j];
    float h_r = ghb[j], h_z = ghb[H_SZ + j], h_n = ghb[2 * H_SZ + j];
    float r = 1.f / (1.f + expf(-(i_r + h_r)));
    float z = 1.f / (1.f + expf(-(i_z + h_z)));
    float n = tanhf(i_n + r * h_n);
    float h = hidden[idx];
    float hn = (1.f - z) * n + z * h;
    h_new[idx] = hn;
    if (hb16) hb16[idx] = (short)f2bf_bits(hn);
}

// ---------------------------------------------------------------------------
// log-softmax, 2 passes, float4, online max+sum. One block (1024 thr) per row.
// ---------------------------------------------------------------------------
__global__ __launch_bounds__(1024) void logsoftmax_v2(float* __restrict__ out)
{
    const int b = blockIdx.x;
    float* row = out + (size_t)b * V_SZ;
    const int tid = threadIdx.x;
    const int wave = tid >> 6;
    const int lane = tid & 63;

    const int head = (int)(((16u - ((uintptr_t)row & 15u)) & 15u) >> 2);  // 0..3
    const int nv = (V_SZ - head) >> 2;
    const float4* r4 = (const float4*)(row + head);
    const int tail_start = head + (nv << 2);

    float m = -INFINITY, s = 0.f;
    if (tid < head) {
        float v = row[tid];
        m = v; s = 1.f;
    }
    for (int i = tid; i < nv; i += 1024) {
        float4 v = r4[i];
        float mv = fmaxf(fmaxf(v.x, v.y), fmaxf(v.z, v.w));
        if (mv > m) { s *= expf(m - mv); m = mv; }
        s += expf(v.x - m) + expf(v.y - m) + expf(v.z - m) + expf(v.w - m);
    }
    for (int i = tail_start + tid; i < V_SZ; i += 1024) {
        float v = row[i];
        if (v > m) { s *= expf(m - v); m = v; }
        s += expf(v - m);
    }

    for (int off = 32; off > 0; off >>= 1) {
        float m2 = __shfl_down(m, off);
        float s2 = __shfl_down(s, off);
        float mn = fmaxf(m, m2);
        s = s * expf(m - mn) + s2 * expf(m2 - mn);
        m = mn;
    }
    __shared__ float smax[16], ssum[16], slse;
    if (lane == 0) { smax[wave] = m; ssum[wave] = s; }
    __syncthreads();
    if (tid == 0) {
        float M = smax[0], S = ssum[0];
        for (int w = 1; w < 16; ++w) {
            float mn = fmaxf(M, smax[w]);
            S = S * expf(M - mn) + ssum[w] * expf(smax[w] - mn);
            M = mn;
        }
        slse = M + logf(S);
    }
    __syncthreads();
    const float lse = slse;

    if (tid < head) row[tid] -= lse;
    float4* w4 = (float4*)(row + head);
    for (int i = tid; i < nv; i += 1024) {
        float4 v = r4[i];
        v.x -= lse; v.y -= lse; v.z -= lse; v.w -= lse;
        w4[i] = v;
    }
    for (int i = tail_start + tid; i < V_SZ; i += 1024) row[i] -= lse;
}

// ---------------------------------------------------------------------------
extern "C" void kernel_launch(void* const* d_in, const int* in_sizes, int n_in,
                              void* d_out, int out_size, void* d_ws, size_t ws_size,
                              hipStream_t stream)
{
    const int*   tokens = (const int*)d_in[0];
    const float* hidden = (const float*)d_in[1];
    const float* enc    = (const float*)d_in[2];
    const float* emb    = (const float*)d_in[3];
    const float* attn_W = (const float*)d_in[4];
    const float* attn_b = (const float*)d_in[5];
    const float* comb_W = (const float*)d_in[6];
    const float* comb_b = (const float*)d_in[7];
    const float* W_ih   = (const float*)d_in[8];
    const float* W_hh   = (const float*)d_in[9];
    const float* b_ih   = (const float*)d_in[10];
    const float* b_hh   = (const float*)d_in[11];
    const float* out_W  = (const float*)d_in[12];
    const float* out_b  = (const float*)d_in[13];

    float* out = (float*)d_out;
    float* logits     = out;                                   // [B,V]
    float* h_new      = out + (size_t)B_SZ * V_SZ;             // [B,H]
    float* attn_w_out = h_new + (size_t)B_SZ * H_SZ;           // [B,L]

    // Workspace: bf16 A-operands (cat16, x16, hin16, hb16) + fp32 gi/gh.
    const size_t need = (size_t)B_SZ * 5 * H_SZ * sizeof(short)
                      + (size_t)B_SZ * 6 * H_SZ * sizeof(float);
    const bool use_ws = (d_ws != nullptr) && (ws_size >= need);

    if (use_ws) {
        short* cat16 = (short*)d_ws;                               // [B,2H]
        short* x16   = cat16 + (size_t)B_SZ * 2 * H_SZ;            // [B,H]
        short* hin16 = x16   + (size_t)B_SZ * H_SZ;                // [B,H]
        short* hb16  = hin16 + (size_t)B_SZ * H_SZ;                // [B,H]
        float* gi    = (float*)(hb16 + (size_t)B_SZ * H_SZ);       // [B,3H]
        float* gh    = gi + (size_t)B_SZ * 3 * H_SZ;               // [B,3H]

        attn_kernel<<<B_SZ, 256, 0, stream>>>(tokens, hidden, enc, emb, attn_W,
                                              attn_b, nullptr, cat16, hin16,
                                              attn_w_out);
        // x16 = bf16(relu(cat @ comb_W^T + comb_b))   [256 x 1024, K=2048]
        gemm_k<1, 1, 4, 1><<<dim3(H_SZ / 64, 4), 256, 0, stream>>>(
            cat16, comb_W, comb_b, nullptr, x16, H_SZ, 2 * H_SZ);
        // gi = x @ W_ih^T + b_ih ; gh = h @ W_hh^T + b_hh   (one dispatch)
        gemm_dual<1, 0, 4, 1><<<dim3(3 * H_SZ / 64, 4, 2), 256, 0, stream>>>(
            x16, W_ih, b_ih, gi, hin16, W_hh, b_hh, gh, 3 * H_SZ, H_SZ);
        gru_combine<<<(B_SZ * H_SZ + 255) / 256, 256, 0, stream>>>(
            gi, gh, hidden, h_new, hb16);
        // logits = h_new @ out_W^T + out_b            [256 x 50257, K=1024]
        gemm_k<4, 0, 3, 1><<<dim3((V_SZ + 63) / 64, 1), 256, 0, stream>>>(
            hb16, out_W, out_b, logits, nullptr, V_SZ, H_SZ);
    } else {
        // Fallback: fp32 scratch carved from logits region (dead before the
        // big GEMM); big GEMM reads h_new (output region, safe) as fp32 A.
        float* cat = logits;                           // [B,2H]
        float* x   = cat + (size_t)B_SZ * 2 * H_SZ;    // [B,H]
        float* gi  = x   + (size_t)B_SZ * H_SZ;        // [B,3H]
        float* gh  = gi  + (size_t)B_SZ * 3 * H_SZ;    // [B,3H]

        attn_kernel<<<B_SZ, 256, 0, stream>>>(tokens, hidden, enc, emb, attn_W,
                                              attn_b, cat, nullptr, nullptr,
                                              attn_w_out);
        gemm_k<1, 1, 3, 0><<<dim3(H_SZ / 64, 4), 256, 0, stream>>>(
            cat, comb_W, comb_b, x, nullptr, H_SZ, 2 * H_SZ);
        gemm_dual<1, 0, 3, 0><<<dim3(3 * H_SZ / 64, 4, 2), 256, 0, stream>>>(
            x, W_ih, b_ih, gi, hidden, W_hh, b_hh, gh, 3 * H_SZ, H_SZ);
        gru_combine<<<(B_SZ * H_SZ + 255) / 256, 256, 0, stream>>>(
            gi, gh, hidden, h_new, nullptr);
        gemm_k<4, 0, 2, 0><<<dim3((V_SZ + 63) / 64, 1), 256, 0, stream>>>(
            h_new, out_W, out_b, logits, nullptr, V_SZ, H_SZ);
    }
    logsoftmax_v2<<<B_SZ, 1024, 0, stream>>>(logits);
}